// Round 9
// baseline (129.366 us; speedup 1.0000x reference)
//
#include <hip/hip_runtime.h>
#include <stdint.h>

#define NB 16
#define NC 128
#define NOC 128
#define NF 64
#define NT 256
#define NCTX 128
#define NTAPS 9
#define NFLAT 147456
#define TEMPR 30.0f

// LDS: X only. 16B chunk = 8 bf16 ic elems. chunks [r:3][kq:4][col:130]
#define SXCOLS 130
#define SX_CH (3*4*SXCOLS)    // 1560 chunks = 24960 B

typedef float f32x4 __attribute__((ext_vector_type(4)));
typedef __bf16 bf16x8 __attribute__((ext_vector_type(8)));

// ---------------- kernel 1: attention (16 x softmax over 4) ----------------
__global__ void attn_kernel(const float* __restrict__ g,
                            const float* __restrict__ dk,
                            const float* __restrict__ bias,
                            float* __restrict__ att) {
    int b = threadIdx.x;
    if (b >= NB) return;
    float r0 = bias[0], r1 = bias[1], r2 = bias[2], r3 = bias[3];
    const float* gb = g + b * NCTX;
    for (int c = 0; c < NCTX; ++c) {
        float gv = gb[c];
        r0 += gv * dk[c*4+0];
        r1 += gv * dk[c*4+1];
        r2 += gv * dk[c*4+2];
        r3 += gv * dk[c*4+3];
    }
    r0 *= (1.0f/TEMPR); r1 *= (1.0f/TEMPR); r2 *= (1.0f/TEMPR); r3 *= (1.0f/TEMPR);
    float mx = fmaxf(fmaxf(r0, r1), fmaxf(r2, r3));
    float e0 = expf(r0-mx), e1 = expf(r1-mx), e2 = expf(r2-mx), e3 = expf(r3-mx);
    float s = e0+e1+e2+e3;
    att[b*4+0] = e0/s; att[b*4+1] = e1/s; att[b*4+2] = e2/s; att[b*4+3] = e3/s;
}

// ------- kernel 2: blend 4 banks -> bf16 W K-major: [b][c4:4][tap:9][kq:4][oc:128][8]
// A lane's MFMA A-fragment (oc=l15, k=l4*8+e) is one contiguous 16B chunk.
__global__ void agg_kernel(const float* __restrict__ w,
                           const float* __restrict__ att,
                           unsigned short* __restrict__ wb) {
    int idx = blockIdx.x * 256 + threadIdx.x;   // 16*128*128 = 262144
    int ic = idx & 127;
    int oc = (idx >> 7) & 127;
    int b  = idx >> 14;
    float a0 = att[b*4+0], a1 = att[b*4+1], a2 = att[b*4+2], a3 = att[b*4+3];
    int d0 = (oc*NC + ic) * NTAPS;
    int c4 = ic >> 5;
    int kq = (ic >> 3) & 3;
    int e  = ic & 7;
    #pragma unroll
    for (int tap = 0; tap < NTAPS; ++tap) {
        float s = a0 * w[0*NFLAT + d0 + tap]
                + a1 * w[1*NFLAT + d0 + tap]
                + a2 * w[2*NFLAT + d0 + tap]
                + a3 * w[3*NFLAT + d0 + tap];
        __bf16 h = (__bf16)s;
        unsigned short u = *(unsigned short*)&h;
        int chunk = (tap * 4 + kq) * 128 + oc;                    // within c4 block
        wb[(((b * 4 + c4) * (NTAPS*4*NOC)) + chunk) * 8 + e] = u;
    }
}

// ------------------- kernel 3: MFMA implicit-GEMM conv -------------------
// W bypasses LDS: A-fragments are coalesced b128 GLOBAL loads from the
// L2-resident K-major panel (XCD swizzle keeps each XCD's 2 batches = 588KB
// in its 4MB L2), soft-pipelined one tap ahead. LDS holds only X (25KB) ->
// 256-thr blocks, ~3 blocks/CU co-resident; cross-block TLP hides latency
// (R6-R8 showed intra-block pipelining can't, at 1 block/CU).
__global__ __launch_bounds__(256) void conv_kernel(
        const float* __restrict__ x,
        const unsigned short* __restrict__ wb,
        float* __restrict__ out) {
    __shared__ __align__(16) unsigned short sx[SX_CH * 8];

    // bijective XCD swizzle: 2048 blocks -> 256 contiguous logical per XCD = 2 batches
    const int p_  = blockIdx.x;
    const int lg  = (p_ & 7) * 256 + (p_ >> 3);
    const int b   = lg >> 7;            // batch
    const int y   = (lg >> 1) & 63;     // output row
    const int t0  = (lg & 1) * 128;     // t half

    const int tid  = threadIdx.x;
    const int lane = tid & 63;
    const int wid  = tid >> 6;
    const int wpix = wid & 1;    // 64-pix half
    const int woc  = wid >> 1;   // 64-oc half
    const int l15  = lane & 15;
    const int l4   = lane >> 4;

    f32x4 acc[4][4];
    #pragma unroll
    for (int m = 0; m < 4; ++m)
        #pragma unroll
        for (int n = 0; n < 4; ++n)
            acc[m][n] = (f32x4){0.f, 0.f, 0.f, 0.f};

    const float* xb = x + (b * NC) * (NF * NT);
    const unsigned short* wbb = wb + b * (4 * NTAPS * 4 * NOC) * 8;

    // A-fragment global base for this thread (adds (tap*4)*128*8 per tap, m*16*8 per m)
    const unsigned short* const wfrag = wbb + (l4 * 128 + woc * 64 + l15) * 8;

    // B-fragment LDS base (chunk (ky*4+l4)*130 + wpix*64 + n*16 + l15 + kx)
    const unsigned short* const sxp = sx + (l4 * SXCOLS + wpix * 64 + l15) * 8;

    for (int c4 = 0; c4 < 4; ++c4) {
        const int ic0 = c4 * 32;
        const unsigned short* const wc4 = wfrag + (c4 * NTAPS * 4 * NOC) * 8;

        // prefetch tap 0's A-fragments (independent of LDS/barriers)
        bf16x8 afc0 = *(const bf16x8*)(wc4 + (0 * 16) * 8);
        bf16x8 afc1 = *(const bf16x8*)(wc4 + (1 * 16) * 8);
        bf16x8 afc2 = *(const bf16x8*)(wc4 + (2 * 16) * 8);
        bf16x8 afc3 = *(const bf16x8*)(wc4 + (3 * 16) * 8);

        __syncthreads();   // previous compute done reading sx

        // ---- stage X: 3 rows x 128 t (+2 halo cols) x 32 ic, fp32->bf16, K-major
        // 1536 main units: e=u&3 (ic pair), kq=(u>>2)&3, q=(u>>4)&31, r=u>>9
        #pragma unroll
        for (int j = 0; j < 6; ++j) {
            const int u  = tid + j * 256;
            const int e  = u & 3;
            const int kq = (u >> 2) & 3;
            const int q  = (u >> 4) & 31;
            const int r  = u >> 9;
            const int iy = y - 1 + r;
            const int ic = ic0 + kq * 8 + e * 2;
            f32x4 v0 = (f32x4){0.f,0.f,0.f,0.f};
            f32x4 v1 = v0;
            if ((unsigned)iy < (unsigned)NF) {
                const float* src = xb + (ic * NF + iy) * NT + t0 + q * 4;
                v0 = *(const f32x4*)src;
                v1 = *(const f32x4*)(src + NF * NT);
            }
            unsigned short* dst = sx + ((r * 4 + kq) * SXCOLS + q * 4 + 1) * 8 + e * 2;
            #pragma unroll
            for (int jj = 0; jj < 4; ++jj) {
                __bf16 h0 = (__bf16)v0[jj];
                __bf16 h1 = (__bf16)v1[jj];
                unsigned pk = (unsigned)*(unsigned short*)&h0
                            | ((unsigned)*(unsigned short*)&h1 << 16);
                *(unsigned*)(dst + jj * 8) = pk;
            }
        }
        // 96 boundary units: cols 0 and 129 (t = t0-1, t0+128; zero if out of range)
        if (tid < 96) {
            const int e    = tid & 3;
            const int kq   = (tid >> 2) & 3;
            const int side = (tid >> 4) & 1;
            const int r    = tid >> 5;
            const int c    = side ? (SXCOLS - 1) : 0;
            const int t    = t0 - 1 + c;
            const int iy   = y - 1 + r;
            const int ic   = ic0 + kq * 8 + e * 2;
            float f0 = 0.f, f1 = 0.f;
            if ((unsigned)iy < (unsigned)NF && (unsigned)t < (unsigned)NT) {
                const float* src = xb + (ic * NF + iy) * NT + t;
                f0 = src[0];
                f1 = src[NF * NT];
            }
            __bf16 h0 = (__bf16)f0;
            __bf16 h1 = (__bf16)f1;
            unsigned pk = (unsigned)*(unsigned short*)&h0
                        | ((unsigned)*(unsigned short*)&h1 << 16);
            *(unsigned*)(sx + ((r * 4 + kq) * SXCOLS + c) * 8 + e * 2) = pk;
        }
        __syncthreads();

        // ---- compute: 9 taps; A from global (1 tap ahead), B from LDS
        #pragma unroll
        for (int tap = 0; tap < 9; ++tap) {
            const int ky = tap / 3;
            const int kx = tap % 3;
            bf16x8 afn0, afn1, afn2, afn3;
            if (tap < 8) {
                const unsigned short* wt = wc4 + ((tap + 1) * 4 * NOC) * 8;
                afn0 = *(const bf16x8*)(wt + (0 * 16) * 8);
                afn1 = *(const bf16x8*)(wt + (1 * 16) * 8);
                afn2 = *(const bf16x8*)(wt + (2 * 16) * 8);
                afn3 = *(const bf16x8*)(wt + (3 * 16) * 8);
            }
            bf16x8 bfv[4];
            #pragma unroll
            for (int n = 0; n < 4; ++n)
                bfv[n] = *(const bf16x8*)(sxp + (ky * 4 * SXCOLS + n * 16 + kx) * 8);
            #pragma unroll
            for (int n = 0; n < 4; ++n) {
                acc[0][n] = __builtin_amdgcn_mfma_f32_16x16x32_bf16(afc0, bfv[n], acc[0][n], 0, 0, 0);
                acc[1][n] = __builtin_amdgcn_mfma_f32_16x16x32_bf16(afc1, bfv[n], acc[1][n], 0, 0, 0);
                acc[2][n] = __builtin_amdgcn_mfma_f32_16x16x32_bf16(afc2, bfv[n], acc[2][n], 0, 0, 0);
                acc[3][n] = __builtin_amdgcn_mfma_f32_16x16x32_bf16(afc3, bfv[n], acc[3][n], 0, 0, 0);
            }
            if (tap < 8) { afc0 = afn0; afc1 = afn1; afc2 = afn2; afc3 = afn3; }
        }
    }

    // ---- epilogue: D[row=oc=(l>>4)*4+r][col=pix=l&15]
    #pragma unroll
    for (int m = 0; m < 4; ++m) {
        int ocb = woc * 64 + m * 16 + l4 * 4;
        #pragma unroll
        for (int r = 0; r < 4; ++r) {
            float* orow = out + ((b * NOC + ocb + r) * NF + y) * NT + t0;
            #pragma unroll
            for (int n = 0; n < 4; ++n)
                orow[wpix * 64 + n * 16 + l15] = acc[m][n][r];
        }
    }
}

extern "C" void kernel_launch(void* const* d_in, const int* in_sizes, int n_in,
                              void* d_out, int out_size, void* d_ws, size_t ws_size,
                              hipStream_t stream) {
    const float* x    = (const float*)d_in[0];
    const float* g    = (const float*)d_in[1];
    const float* dk   = (const float*)d_in[2];
    const float* bias = (const float*)d_in[3];
    const float* w    = (const float*)d_in[4];
    float* out = (float*)d_out;

    float* att = (float*)d_ws;                                  // 64 floats
    unsigned short* wb = (unsigned short*)((char*)d_ws + 256);  // 16*9*128*128 bf16, K-major

    attn_kernel<<<dim3(1), dim3(64), 0, stream>>>(g, dk, bias, att);
    agg_kernel<<<dim3(1024), dim3(256), 0, stream>>>(w, att, wb);
    conv_kernel<<<dim3(2048), dim3(256), 0, stream>>>(x, wb, out);
}